// Round 4
// baseline (42.496 us; speedup 1.0000x reference)
//
#include <hip/hip_runtime.h>
#include <hip/hip_bf16.h>

// Problem constants (from reference)
constexpr int ROWS = 4096;
constexpr int COLS = 11008;
constexpr int CODEBOOK_NUM = 2;
constexpr int CENTROIDS_NUM = 256;
constexpr int VEC_DIM = 4;
constexpr long long N_VECS = (long long)ROWS * COLS / VEC_DIM;   // 11,272,192
constexpr long long HALF_VECS = N_VECS / CODEBOOK_NUM;           // 5,636,096 = 1376 * 4096

typedef float f32x4 __attribute__((ext_vector_type(4)));

// Block = 256 threads; each block covers 4096 consecutive vectors.
// Thread (wave w, lane l) handles vectors vbase + k*64, k=0..15, where
// vbase = blk*4096 + w*1024 + l  -> every load/store instruction in a wave
// touches a fully contiguous range:
//   codes:  64 lanes x 4 B   = 256 B contiguous per instruction (NT stream)
//   out:    64 lanes x 16 B  = 1 KB contiguous per instruction (plain store, L2 WC)
// HALF_VECS % 4096 == 0 -> codebook-half offset is block-uniform.
__global__ __launch_bounds__(256) void dequant_kernel(
    const int* __restrict__ codes,
    const float* __restrict__ codebooks,
    const float* __restrict__ scales,
    f32x4* __restrict__ out4)
{
    __shared__ f32x4 cb[CODEBOOK_NUM * CENTROIDS_NUM];  // 8 KB

    const int tid = threadIdx.x;
    const f32x4* cb_g = reinterpret_cast<const f32x4*>(codebooks);
    cb[tid]       = cb_g[tid];
    cb[tid + 256] = cb_g[tid + 256];
    __syncthreads();

    const int lane = tid & 63;
    const int wave = tid >> 6;
    // wave w owns a contiguous 1024-vector span within the block's 4096
    const long long vbase = (long long)blockIdx.x * 4096 + wave * 1024 + lane;
    const int off = (vbase < HALF_VECS) ? 0 : CENTROIDS_NUM;   // block-uniform

    // Issue all global reads first (memory-level parallelism: 32 loads in flight)
    int   c[16];
    float s[16];
#pragma unroll
    for (int k = 0; k < 16; ++k) {
        const long long v = vbase + (long long)k * 64;
        c[k] = __builtin_nontemporal_load(&codes[v]);
        s[k] = scales[v >> 4];
    }

#pragma unroll
    for (int k = 0; k < 16; ++k) {
        const long long v = vbase + (long long)k * 64;
        f32x4 e = cb[c[k] + off];
        e *= s[k];
        out4[v] = e;   // plain store: full-line write-combining through L2
    }
}

extern "C" void kernel_launch(void* const* d_in, const int* in_sizes, int n_in,
                              void* d_out, int out_size, void* d_ws, size_t ws_size,
                              hipStream_t stream) {
    const int*   codes     = (const int*)d_in[0];
    const float* codebooks = (const float*)d_in[1];
    const float* scales    = (const float*)d_in[2];
    f32x4*       out4      = (f32x4*)d_out;

    const int block = 256;
    const int grid = (int)(N_VECS / 4096);   // 2752, exact
    dequant_kernel<<<grid, block, 0, stream>>>(codes, codebooks, scales, out4);
}

// Round 5
// 40.254 us; speedup vs baseline: 1.0557x; 1.0557x over previous
//
#include <hip/hip_runtime.h>
#include <hip/hip_bf16.h>

// Problem constants (from reference)
constexpr int ROWS = 4096;
constexpr int COLS = 11008;
constexpr int CODEBOOK_NUM = 2;
constexpr int CENTROIDS_NUM = 256;
constexpr int VEC_DIM = 4;
constexpr long long N_VECS = (long long)ROWS * COLS / VEC_DIM;   // 11,272,192
constexpr long long HALF_VECS = N_VECS / CODEBOOK_NUM;           // 5,636,096 = 2752 * 2048

typedef float f32x4 __attribute__((ext_vector_type(4)));

// Block = 256 threads; each block covers 2048 consecutive vectors.
// Thread (wave w, lane l) handles vectors vbase + k*64, k=0..7, where
// vbase = blk*2048 + w*512 + l  -> every load/store instruction in a wave
// touches a fully contiguous range:
//   codes:  64 lanes x 4 B   = 256 B contiguous per instruction (NT: stream once)
//   out:    64 lanes x 16 B  = 1 KB contiguous per instruction (plain store, L2 WC)
// HALF_VECS % 2048 == 0 -> codebook-half offset is block-uniform.
// NOTE R4 lesson: 16-deep unroll regressed (42.5 us vs 40.2) — register
// pressure with no latency benefit. 8-deep is the measured sweet spot.
__global__ __launch_bounds__(256) void dequant_kernel(
    const int* __restrict__ codes,
    const float* __restrict__ codebooks,
    const float* __restrict__ scales,
    f32x4* __restrict__ out4)
{
    __shared__ f32x4 cb[CODEBOOK_NUM * CENTROIDS_NUM];  // 8 KB

    const int tid = threadIdx.x;
    const f32x4* cb_g = reinterpret_cast<const f32x4*>(codebooks);
    cb[tid]       = cb_g[tid];
    cb[tid + 256] = cb_g[tid + 256];
    __syncthreads();

    const int lane = tid & 63;
    const int wave = tid >> 6;
    // wave w owns a contiguous 512-vector span within the block's 2048
    const long long vbase = (long long)blockIdx.x * 2048 + wave * 512 + lane;
    const int off = (vbase < HALF_VECS) ? 0 : CENTROIDS_NUM;   // block-uniform

    // Issue all global reads first (memory-level parallelism: 16 loads in flight)
    int   c[8];
    float s[8];
#pragma unroll
    for (int k = 0; k < 8; ++k) {
        const long long v = vbase + (long long)k * 64;
        c[k] = __builtin_nontemporal_load(&codes[v]);
        s[k] = scales[v >> 4];
    }

#pragma unroll
    for (int k = 0; k < 8; ++k) {
        const long long v = vbase + (long long)k * 64;
        f32x4 e = cb[c[k] + off];
        e *= s[k];
        out4[v] = e;   // plain store: full-line write-combining through L2
    }
}

extern "C" void kernel_launch(void* const* d_in, const int* in_sizes, int n_in,
                              void* d_out, int out_size, void* d_ws, size_t ws_size,
                              hipStream_t stream) {
    const int*   codes     = (const int*)d_in[0];
    const float* codebooks = (const float*)d_in[1];
    const float* scales    = (const float*)d_in[2];
    f32x4*       out4      = (f32x4*)d_out;

    const int block = 256;
    const int grid = (int)(N_VECS / 2048);   // 2752, exact
    dequant_kernel<<<grid, block, 0, stream>>>(codes, codebooks, scales, out4);
}